// Round 14
// baseline (5396.747 us; speedup 1.0000x reference)
//
#include <hip/hip_runtime.h>
#include <math.h>

#define B_SZ   32
#define T_SZ   1024
#define IN_SZ  512
#define SEN    512
#define HID    1024
#define MOT    512
#define OUT_SZ 512

#define NBLK   32          // scan blocks (j-slices)
#define JSL    32          // j's per block
#define K2     512         // f16-pair dwords per h row
#define WPAD   516         // padded w_lds row stride (dwords)
#define NWV    128         // scan waves (flags)

typedef __fp16  f16x8 __attribute__((ext_vector_type(8)));
typedef float   f32x4 __attribute__((ext_vector_type(4)));

__device__ inline uint32_t pk16(float a, float b) {
  auto p = __builtin_amdgcn_cvt_pkrtz(a, b);
  return __builtin_bit_cast(uint32_t, p);
}

// ---------------------------------------------------------------------------
// f32 tile GEMM (K0 only): C = A @ B (+bias), generalized scatter
// ---------------------------------------------------------------------------
template<bool TB>
__global__ __launch_bounds__(256) void gemm_tiled(
    const float* __restrict__ A, const float* __restrict__ Bm,
    const float* __restrict__ bias, float* __restrict__ C,
    int M, int N, int K, int lda,
    int P, long long S1, long long S2)
{
  __shared__ float As[16][64 + 1];
  __shared__ float Bs[16][64 + 1];
  const int tid = threadIdx.x;
  const int n0 = blockIdx.x * 64;
  const int r0 = blockIdx.y * 64;
  const int ty = tid / 16;
  const int tx = tid % 16;

  float acc[4][4] = {};

  for (int k0 = 0; k0 < K; k0 += 16) {
    {
      const int kk = tid % 16, m0 = tid / 16;
      #pragma unroll
      for (int i = 0; i < 4; i++) {
        const int m = m0 + i * 16;
        As[kk][m] = A[(long long)(r0 + m) * lda + k0 + kk];
      }
    }
    if (TB) {
      const int kk = tid % 16, nl0 = tid / 16;
      #pragma unroll
      for (int i = 0; i < 4; i++) {
        const int n = nl0 + i * 16;
        Bs[kk][n] = Bm[(long long)(n0 + n) * K + k0 + kk];
      }
    } else {
      const int nl = tid % 64, kk0 = tid / 64;
      #pragma unroll
      for (int i = 0; i < 4; i++) {
        const int kk = kk0 + i * 4;
        Bs[kk][nl] = Bm[(long long)(k0 + kk) * N + n0 + nl];
      }
    }
    __syncthreads();

    #pragma unroll
    for (int kk = 0; kk < 16; kk++) {
      float av[4], bv[4];
      #pragma unroll
      for (int i = 0; i < 4; i++) av[i] = As[kk][ty * 4 + i];
      #pragma unroll
      for (int j = 0; j < 4; j++) bv[j] = Bs[kk][tx * 4 + j];
      #pragma unroll
      for (int i = 0; i < 4; i++)
        #pragma unroll
        for (int j = 0; j < 4; j++)
          acc[i][j] += av[i] * bv[j];
    }
    __syncthreads();
  }

  #pragma unroll
  for (int i = 0; i < 4; i++) {
    const int r = r0 + ty * 4 + i;
    const long long base = (long long)(r % P) * S1 + (long long)(r / P) * S2;
    #pragma unroll
    for (int j = 0; j < 4; j++) {
      const int c = n0 + tx * 4 + j;
      float v = acc[i][j];
      if (bias) v += bias[c];
      C[base + c] = v;
    }
  }
}

// ---------------------------------------------------------------------------
// MFMA f16 GEMM (R13-verified): C[scatter(r), c] = sum_k A[r,k]*B[c,k] + bias
// ---------------------------------------------------------------------------
__global__ __launch_bounds__(256) void gemm_mfma(
    const uint32_t* __restrict__ A16, const uint32_t* __restrict__ B16,
    const float* __restrict__ bias, float* __restrict__ C,
    int K2w, int P, long long S1, long long S2)
{
  __shared__ uint32_t Al[128 * 20];
  __shared__ uint32_t Bl[128 * 20];
  const int tid  = threadIdx.x;
  const int r0   = blockIdx.y * 128;
  const int c0   = blockIdx.x * 128;
  const int wv   = tid >> 6, lane = tid & 63;
  const int wrow = wv >> 1, wcol = wv & 1;
  const int row16 = lane & 15, kg = lane >> 4;

  const int srow = tid >> 1;
  const int scol = (tid & 1) * 8;

  f32x4 acc[4][4];
  #pragma unroll
  for (int a = 0; a < 4; ++a)
    #pragma unroll
    for (int b = 0; b < 4; ++b) acc[a][b] = (f32x4){0.f, 0.f, 0.f, 0.f};

  const int nkt = K2w / 16;
  for (int kt = 0; kt < nkt; ++kt) {
    const uint32_t* ag = A16 + (size_t)(r0 + srow) * K2w + kt * 16 + scol;
    const uint32_t* bg = B16 + (size_t)(c0 + srow) * K2w + kt * 16 + scol;
    *(uint4*)&Al[srow * 20 + scol]     = *(const uint4*)ag;
    *(uint4*)&Al[srow * 20 + scol + 4] = *(const uint4*)(ag + 4);
    *(uint4*)&Bl[srow * 20 + scol]     = *(const uint4*)bg;
    *(uint4*)&Bl[srow * 20 + scol + 4] = *(const uint4*)(bg + 4);
    __syncthreads();

    uint4 af[4], bf[4];
    #pragma unroll
    for (int f = 0; f < 4; ++f) {
      af[f] = *(const uint4*)&Al[(wrow * 64 + f * 16 + row16) * 20 + kg * 4];
      bf[f] = *(const uint4*)&Bl[(wcol * 64 + f * 16 + row16) * 20 + kg * 4];
    }
    #pragma unroll
    for (int fr = 0; fr < 4; ++fr)
      #pragma unroll
      for (int fc = 0; fc < 4; ++fc)
        acc[fr][fc] = __builtin_amdgcn_mfma_f32_16x16x32_f16(
            __builtin_bit_cast(f16x8, af[fr]), __builtin_bit_cast(f16x8, bf[fc]),
            acc[fr][fc], 0, 0, 0);
    __syncthreads();
  }

  #pragma unroll
  for (int fr = 0; fr < 4; ++fr) {
    #pragma unroll
    for (int reg = 0; reg < 4; ++reg) {
      const int rg = r0 + wrow * 64 + fr * 16 + kg * 4 + reg;
      const long long base = (long long)(rg % P) * S1 + (long long)(rg / P) * S2;
      #pragma unroll
      for (int fc = 0; fc < 4; ++fc) {
        const int cg = c0 + wcol * 64 + fc * 16 + row16;
        C[base + cg] = acc[fr][fc][reg] + (bias ? bias[cg] : 0.f);
      }
    }
  }
}

// bias_eff[h] = b_cell[h] + dot(W_x[h,:], b_in)
__global__ void bias_eff_kernel(const float* __restrict__ Wx,
                                const float* __restrict__ b_in,
                                const float* __restrict__ b_cell,
                                float* __restrict__ bias_eff)
{
  const int h = blockIdx.x * 256 + threadIdx.x;
  float s = b_cell[h];
  for (int k = 0; k < SEN; k++) s += Wx[h * SEN + k] * b_in[k];
  bias_eff[h] = s;
}

// Generic f32 -> f16-pair pack
__global__ __launch_bounds__(256) void pack16_kernel(
    const float* __restrict__ in, uint32_t* __restrict__ outp)
{
  const size_t idx = (size_t)blockIdx.x * 256 + threadIdx.x;
  const float2 v = *(const float2*)(in + idx * 2);
  outp[idx] = pk16(v.x, v.y);
}

// Pack init_h -> hx[0] fragment-major: u32 idx = (j2>>2)*128 + b*4 + (j2&3)
__global__ __launch_bounds__(256) void init_hx_kernel(
    const float* __restrict__ init_h, uint32_t* __restrict__ hx0)
{
  const int idx = blockIdx.x * 256 + threadIdx.x;
  const int b  = idx >> 9;
  const int j2 = idx & 511;
  const float2 v = *(const float2*)(init_h + (size_t)b * HID + 2 * j2);
  hx0[(j2 >> 2) * 128 + b * 4 + (j2 & 3)] = pk16(v.x, v.y);
}

// ---------------------------------------------------------------------------
// Scan v11: PER-WAVE flags, ZERO in-loop __syncthreads.
// 32 blocks x 256 threads = 128 independent waves. Per wave per step:
//   poll all 128 wave-flags >= t (2/lane + __all)
//   -> 64x coherent 8B A-loads (fragment-major, coalesced)
//   -> 32 MFMA -> liquid update (exact f32 h_old in regs)
//   -> 4 hx publishes -> s_waitcnt vmcnt(0) -> lane0 posts flag[wid]=t+1
//   -> hseq16 stores + pre/ts prefetch (OFF the inter-block critical path)
// Correctness: flag=t+1 implies (vmcnt0) wave's t-reads AND t+1-publishes
// done -> parity overwrite safe + data visible (same invariant as R11).
// ---------------------------------------------------------------------------
__global__ __launch_bounds__(256, 1) void scan_x_kernel(
    const float* __restrict__ init_h,
    const uint32_t* __restrict__ Wp16,   // [HID][K2]
    const float* __restrict__ pre,       // [T][B][HID]
    const float* __restrict__ tsp,       // [B][T]
    const float* __restrict__ Avec,
    const float* __restrict__ tau,
    uint32_t* __restrict__ hseq16,       // [T][B][256] f16 pairs
    uint32_t* __restrict__ hx,           // [2][B_SZ*K2] fragment-major
    uint32_t* __restrict__ flags,        // [NWV][16]
    float* __restrict__ last_state)      // [B][HID]
{
  __shared__ uint32_t w_lds[JSL * WPAD];   // 66 KB

  const int bk   = blockIdx.x;
  const int tid  = threadIdx.x;
  const int wv   = tid >> 6;
  const int lane = tid & 63;
  const int wid  = bk * 4 + wv;            // 0..127
  const int qr   = wv >> 1;
  const int qc   = wv & 1;
  const int row16 = lane & 15;
  const int kg    = lane >> 4;

  const int j_loc  = qc * 16 + row16;
  const int j_glob = bk * JSL + j_loc;
  const int b0     = qr * 16 + kg * 4;

  {
    const uint32_t* src = Wp16 + (size_t)bk * JSL * K2;
    for (int i = tid; i < JSL * K2; i += 256)
      w_lds[(i >> 9) * WPAD + (i & (K2 - 1))] = src[i];
  }

  const float a_j  = Avec[j_glob];
  const float it_j = 1.f / tau[j_glob];
  float h_old[4];
  #pragma unroll
  for (int r = 0; r < 4; ++r) h_old[r] = init_h[(b0 + r) * HID + j_glob];

  float prevC[4], tsC[4];
  #pragma unroll
  for (int r = 0; r < 4; ++r) {
    prevC[r] = pre[(size_t)(b0 + r) * HID + j_glob];
    tsC[r]   = tsp[(b0 + r) * T_SZ + 0];
  }

  __syncthreads();   // w_lds ready (only barrier in the kernel)

  const uint32_t* brow = &w_lds[j_loc * WPAD];
  const int ab2 = (qr * 16 + row16) * 2;            // u64 base within chunk
  const int pub_base = (j_glob >> 3) * 128 + ((j_glob >> 1) & 3);

  for (int t = 0; t < T_SZ; ++t) {
    // poll: all 128 wave-flags >= t  (flags start at 0 == "step-0 published")
    {
      const uint32_t tgt = (uint32_t)t;
      while (true) {
        const uint32_t v0 = __hip_atomic_load(&flags[lane * 16],
                              __ATOMIC_RELAXED, __HIP_MEMORY_SCOPE_AGENT);
        const uint32_t v1 = __hip_atomic_load(&flags[(lane + 64) * 16],
                              __ATOMIC_RELAXED, __HIP_MEMORY_SCOPE_AGENT);
        if (__all((v0 >= tgt) && (v1 >= tgt))) break;
        __builtin_amdgcn_s_sleep(1);
      }
    }

    // A fragments (coalesced coherent 8B loads)
    const unsigned long long* hxr =
        (const unsigned long long*)(hx + (t & 1) * (B_SZ * K2));
    unsigned long long a64[64];
    #pragma unroll
    for (int kk = 0; kk < 32; ++kk) {
      const size_t base = (size_t)(kk * 4 + kg) * 64 + ab2;
      a64[2 * kk]     = __hip_atomic_load(&hxr[base],
                          __ATOMIC_RELAXED, __HIP_MEMORY_SCOPE_AGENT);
      a64[2 * kk + 1] = __hip_atomic_load(&hxr[base + 1],
                          __ATOMIC_RELAXED, __HIP_MEMORY_SCOPE_AGENT);
    }

    f32x4 acc = {0.f, 0.f, 0.f, 0.f};
    #pragma unroll
    for (int kk = 0; kk < 32; ++kk) {
      const uint4 av = make_uint4((uint32_t)a64[2 * kk],
                                  (uint32_t)(a64[2 * kk] >> 32),
                                  (uint32_t)a64[2 * kk + 1],
                                  (uint32_t)(a64[2 * kk + 1] >> 32));
      const uint4 bv = *(const uint4*)(brow + kk * 16 + kg * 4);
      acc = __builtin_amdgcn_mfma_f32_16x16x32_f16(
          __builtin_bit_cast(f16x8, av), __builtin_bit_cast(f16x8, bv),
          acc, 0, 0, 0);
    }

    float hn[4];
    #pragma unroll
    for (int r = 0; r < 4; ++r) {
      const float z = acc[r] + prevC[r];
      const float f = 1.f / (1.f + __expf(-z));
      hn[r] = (h_old[r] + tsC[r] * f * a_j) / (1.f + tsC[r] * (it_j + f));
      h_old[r] = hn[r];
    }

    uint32_t pkv[4];
    #pragma unroll
    for (int r = 0; r < 4; ++r) {
      const float partner = __shfl_xor(hn[r], 1);
      pkv[r] = pk16(hn[r], partner);
    }

    // publish hx FIRST (critical path), drain, post own flag
    uint32_t* hxw = hx + ((t + 1) & 1) * (B_SZ * K2);
    if ((row16 & 1) == 0) {
      #pragma unroll
      for (int r = 0; r < 4; ++r)
        __hip_atomic_store(&hxw[pub_base + (b0 + r) * 4], pkv[r],
                           __ATOMIC_RELAXED, __HIP_MEMORY_SCOPE_AGENT);
    }
    asm volatile("s_waitcnt vmcnt(0)" ::: "memory");   // my reads+publishes done
    if (lane == 0)
      __hip_atomic_store(&flags[wid * 16], (uint32_t)(t + 1),
                         __ATOMIC_RELAXED, __HIP_MEMORY_SCOPE_AGENT);

    // off-critical-path: hseq16 + next-step prefetch
    if (bk < 16 && (row16 & 1) == 0) {
      #pragma unroll
      for (int r = 0; r < 4; ++r)
        hseq16[(size_t)t * (B_SZ * 256) + (b0 + r) * 256 + (j_glob >> 1)] = pkv[r];
    }
    const int tn = (t + 1 < T_SZ) ? t + 1 : t;
    #pragma unroll
    for (int r = 0; r < 4; ++r) {
      prevC[r] = pre[(size_t)tn * (B_SZ * HID) + (b0 + r) * HID + j_glob];
      tsC[r]   = tsp[(b0 + r) * T_SZ + tn];
    }
  }

  #pragma unroll
  for (int r = 0; r < 4; ++r)
    last_state[(b0 + r) * HID + j_glob] = h_old[r];
}

extern "C" void kernel_launch(void* const* d_in, const int* in_sizes, int n_in,
                              void* d_out, int out_size, void* d_ws, size_t ws_size,
                              hipStream_t stream)
{
  const float* inputs    = (const float*)d_in[0];
  const float* timespans = (const float*)d_in[1];
  const float* init_h    = (const float*)d_in[2];
  const float* W_in      = (const float*)d_in[3];
  const float* b_in      = (const float*)d_in[4];
  const float* W_x       = (const float*)d_in[5];
  const float* W_h       = (const float*)d_in[6];
  const float* b_cell    = (const float*)d_in[7];
  const float* tau       = (const float*)d_in[8];
  const float* A         = (const float*)d_in[9];
  const float* W_out     = (const float*)d_in[10];
  const float* b_out     = (const float*)d_in[11];
  float* out = (float*)d_out;

  float*    ws     = (float*)d_ws;
  float*    pre    = ws;
  uint32_t* hseq16 = (uint32_t*)(pre + (size_t)T_SZ * B_SZ * HID);
  uint32_t* in16   = hseq16 + (size_t)T_SZ * B_SZ * 256;
  float*    Wxi    = (float*)(in16 + (size_t)B_SZ * T_SZ * 256);
  uint32_t* wxi16  = (uint32_t*)(Wxi + (size_t)HID * IN_SZ);
  uint32_t* wh16   = wxi16 + (size_t)HID * (IN_SZ / 2);
  uint32_t* wout16 = wh16 + (size_t)HID * K2;
  float*    beff   = (float*)(wout16 + (size_t)OUT_SZ * (MOT / 2));
  uint32_t* hx     = (uint32_t*)(beff + HID);
  uint32_t* flags  = hx + 2 * B_SZ * K2;                 // NWV*16 u32

  // K0: Wxi = W_x @ W_in (f32)
  gemm_tiled<false><<<dim3(IN_SZ / 64, HID / 64), 256, 0, stream>>>(
      W_x, W_in, nullptr, Wxi, HID, IN_SZ, SEN, SEN,
      1 << 30, (long long)IN_SZ, 0LL);

  bias_eff_kernel<<<HID / 256, 256, 0, stream>>>(W_x, b_in, b_cell, beff);

  // packs
  pack16_kernel<<<(B_SZ * T_SZ * IN_SZ / 2) / 256, 256, 0, stream>>>(inputs, in16);
  pack16_kernel<<<(HID * IN_SZ / 2) / 256, 256, 0, stream>>>(Wxi, wxi16);
  pack16_kernel<<<(HID * HID / 2) / 256, 256, 0, stream>>>(W_h, wh16);
  pack16_kernel<<<(OUT_SZ * MOT / 2) / 256, 256, 0, stream>>>(W_out, wout16);

  // K1 (MFMA): pre = in16 @ wxi16^T + beff, scattered to [t][b][h]
  gemm_mfma<<<dim3(HID / 128, (B_SZ * T_SZ) / 128), 256, 0, stream>>>(
      in16, wxi16, beff, pre, IN_SZ / 2,
      T_SZ, (long long)B_SZ * HID, (long long)HID);

  // init exchange parity-0; zero flags
  init_hx_kernel<<<(B_SZ * K2) / 256, 256, 0, stream>>>(init_h, hx);
  (void)hipMemsetAsync(flags, 0, NWV * 16 * sizeof(uint32_t), stream);

  // scan — 32 co-resident blocks, per-wave flags
  {
    const uint32_t* wh16c = (const uint32_t*)wh16;
    float* last_state = out + (size_t)B_SZ * T_SZ * OUT_SZ;
    void* args[] = {
      (void*)&init_h, (void*)&wh16c, (void*)&pre, (void*)&timespans,
      (void*)&A, (void*)&tau, (void*)&hseq16, (void*)&hx, (void*)&flags,
      (void*)&last_state
    };
    (void)hipLaunchCooperativeKernel((void*)scan_x_kernel, dim3(NBLK), dim3(256),
                                     args, 0, stream);
  }

  // K3 (MFMA): out = hseq16 @ wout16^T + b_out, scattered to [b][t][o]
  gemm_mfma<<<dim3(OUT_SZ / 128, (B_SZ * T_SZ) / 128), 256, 0, stream>>>(
      hseq16, wout16, b_out, out, MOT / 2,
      B_SZ, (long long)T_SZ * OUT_SZ, (long long)OUT_SZ);
}

// Round 15
// 3950.724 us; speedup vs baseline: 1.3660x; 1.3660x over previous
//
#include <hip/hip_runtime.h>
#include <math.h>

#define B_SZ   32
#define T_SZ   1024
#define IN_SZ  512
#define SEN    512
#define HID    1024
#define MOT    512
#define OUT_SZ 512

#define NBLK   32          // scan blocks (j-slices)
#define JSL    32          // j's per block
#define K2     512         // f16-pair dwords per h row
#define WPAD   516         // padded w_lds row stride (dwords)

typedef __fp16  f16x8 __attribute__((ext_vector_type(8)));
typedef float   f32x4 __attribute__((ext_vector_type(4)));

__device__ inline uint32_t pk16(float a, float b) {
  auto p = __builtin_amdgcn_cvt_pkrtz(a, b);
  return __builtin_bit_cast(uint32_t, p);
}

// ---------------------------------------------------------------------------
// f32 tile GEMM (K0 only): C = A @ B (+bias), generalized scatter
// ---------------------------------------------------------------------------
template<bool TB>
__global__ __launch_bounds__(256) void gemm_tiled(
    const float* __restrict__ A, const float* __restrict__ Bm,
    const float* __restrict__ bias, float* __restrict__ C,
    int M, int N, int K, int lda,
    int P, long long S1, long long S2)
{
  __shared__ float As[16][64 + 1];
  __shared__ float Bs[16][64 + 1];
  const int tid = threadIdx.x;
  const int n0 = blockIdx.x * 64;
  const int r0 = blockIdx.y * 64;
  const int ty = tid / 16;
  const int tx = tid % 16;

  float acc[4][4] = {};

  for (int k0 = 0; k0 < K; k0 += 16) {
    {
      const int kk = tid % 16, m0 = tid / 16;
      #pragma unroll
      for (int i = 0; i < 4; i++) {
        const int m = m0 + i * 16;
        As[kk][m] = A[(long long)(r0 + m) * lda + k0 + kk];
      }
    }
    if (TB) {
      const int kk = tid % 16, nl0 = tid / 16;
      #pragma unroll
      for (int i = 0; i < 4; i++) {
        const int n = nl0 + i * 16;
        Bs[kk][n] = Bm[(long long)(n0 + n) * K + k0 + kk];
      }
    } else {
      const int nl = tid % 64, kk0 = tid / 64;
      #pragma unroll
      for (int i = 0; i < 4; i++) {
        const int kk = kk0 + i * 4;
        Bs[kk][nl] = Bm[(long long)(k0 + kk) * N + n0 + nl];
      }
    }
    __syncthreads();

    #pragma unroll
    for (int kk = 0; kk < 16; kk++) {
      float av[4], bv[4];
      #pragma unroll
      for (int i = 0; i < 4; i++) av[i] = As[kk][ty * 4 + i];
      #pragma unroll
      for (int j = 0; j < 4; j++) bv[j] = Bs[kk][tx * 4 + j];
      #pragma unroll
      for (int i = 0; i < 4; i++)
        #pragma unroll
        for (int j = 0; j < 4; j++)
          acc[i][j] += av[i] * bv[j];
    }
    __syncthreads();
  }

  #pragma unroll
  for (int i = 0; i < 4; i++) {
    const int r = r0 + ty * 4 + i;
    const long long base = (long long)(r % P) * S1 + (long long)(r / P) * S2;
    #pragma unroll
    for (int j = 0; j < 4; j++) {
      const int c = n0 + tx * 4 + j;
      float v = acc[i][j];
      if (bias) v += bias[c];
      C[base + c] = v;
    }
  }
}

// ---------------------------------------------------------------------------
// MFMA f16 GEMM (R13-verified): C[scatter(r), c] = sum_k A[r,k]*B[c,k] + bias
// ---------------------------------------------------------------------------
__global__ __launch_bounds__(256) void gemm_mfma(
    const uint32_t* __restrict__ A16, const uint32_t* __restrict__ B16,
    const float* __restrict__ bias, float* __restrict__ C,
    int K2w, int P, long long S1, long long S2)
{
  __shared__ uint32_t Al[128 * 20];
  __shared__ uint32_t Bl[128 * 20];
  const int tid  = threadIdx.x;
  const int r0   = blockIdx.y * 128;
  const int c0   = blockIdx.x * 128;
  const int wv   = tid >> 6, lane = tid & 63;
  const int wrow = wv >> 1, wcol = wv & 1;
  const int row16 = lane & 15, kg = lane >> 4;

  const int srow = tid >> 1;
  const int scol = (tid & 1) * 8;

  f32x4 acc[4][4];
  #pragma unroll
  for (int a = 0; a < 4; ++a)
    #pragma unroll
    for (int b = 0; b < 4; ++b) acc[a][b] = (f32x4){0.f, 0.f, 0.f, 0.f};

  const int nkt = K2w / 16;
  for (int kt = 0; kt < nkt; ++kt) {
    const uint32_t* ag = A16 + (size_t)(r0 + srow) * K2w + kt * 16 + scol;
    const uint32_t* bg = B16 + (size_t)(c0 + srow) * K2w + kt * 16 + scol;
    *(uint4*)&Al[srow * 20 + scol]     = *(const uint4*)ag;
    *(uint4*)&Al[srow * 20 + scol + 4] = *(const uint4*)(ag + 4);
    *(uint4*)&Bl[srow * 20 + scol]     = *(const uint4*)bg;
    *(uint4*)&Bl[srow * 20 + scol + 4] = *(const uint4*)(bg + 4);
    __syncthreads();

    uint4 af[4], bf[4];
    #pragma unroll
    for (int f = 0; f < 4; ++f) {
      af[f] = *(const uint4*)&Al[(wrow * 64 + f * 16 + row16) * 20 + kg * 4];
      bf[f] = *(const uint4*)&Bl[(wcol * 64 + f * 16 + row16) * 20 + kg * 4];
    }
    #pragma unroll
    for (int fr = 0; fr < 4; ++fr)
      #pragma unroll
      for (int fc = 0; fc < 4; ++fc)
        acc[fr][fc] = __builtin_amdgcn_mfma_f32_16x16x32_f16(
            __builtin_bit_cast(f16x8, af[fr]), __builtin_bit_cast(f16x8, bf[fc]),
            acc[fr][fc], 0, 0, 0);
    __syncthreads();
  }

  #pragma unroll
  for (int fr = 0; fr < 4; ++fr) {
    #pragma unroll
    for (int reg = 0; reg < 4; ++reg) {
      const int rg = r0 + wrow * 64 + fr * 16 + kg * 4 + reg;
      const long long base = (long long)(rg % P) * S1 + (long long)(rg / P) * S2;
      #pragma unroll
      for (int fc = 0; fc < 4; ++fc) {
        const int cg = c0 + wcol * 64 + fc * 16 + row16;
        C[base + cg] = acc[fr][fc][reg] + (bias ? bias[cg] : 0.f);
      }
    }
  }
}

// bias_eff[h] = b_cell[h] + dot(W_x[h,:], b_in)
__global__ void bias_eff_kernel(const float* __restrict__ Wx,
                                const float* __restrict__ b_in,
                                const float* __restrict__ b_cell,
                                float* __restrict__ bias_eff)
{
  const int h = blockIdx.x * 256 + threadIdx.x;
  float s = b_cell[h];
  for (int k = 0; k < SEN; k++) s += Wx[h * SEN + k] * b_in[k];
  bias_eff[h] = s;
}

// Generic f32 -> f16-pair pack
__global__ __launch_bounds__(256) void pack16_kernel(
    const float* __restrict__ in, uint32_t* __restrict__ outp)
{
  const size_t idx = (size_t)blockIdx.x * 256 + threadIdx.x;
  const float2 v = *(const float2*)(in + idx * 2);
  outp[idx] = pk16(v.x, v.y);
}

// Pack init_h -> hx[0] fragment-major: u32 idx = (j2>>2)*128 + b*4 + (j2&3)
__global__ __launch_bounds__(256) void init_hx_kernel(
    const float* __restrict__ init_h, uint32_t* __restrict__ hx0)
{
  const int idx = blockIdx.x * 256 + threadIdx.x;
  const int b  = idx >> 9;
  const int j2 = idx & 511;
  const float2 v = *(const float2*)(init_h + (size_t)b * HID + 2 * j2);
  hx0[(j2 >> 2) * 128 + b * 4 + (j2 & 3)] = pk16(v.x, v.y);
}

// ---------------------------------------------------------------------------
// Scan v12 = R13 protocol (block flags + 2 syncthreads) with the drain path
// slimmed: ONLY the 4 hx publishes sit before the drain-sync + flag post;
// hseq16 stores and pre/ts prefetch moved AFTER the flag post (they complete
// under the next poll). Everything else byte-identical to R13.
// ---------------------------------------------------------------------------
__global__ __launch_bounds__(256, 1) void scan_x_kernel(
    const float* __restrict__ init_h,
    const uint32_t* __restrict__ Wp16,   // [HID][K2]
    const float* __restrict__ pre,       // [T][B][HID]
    const float* __restrict__ tsp,       // [B][T]
    const float* __restrict__ Avec,
    const float* __restrict__ tau,
    uint32_t* __restrict__ hseq16,       // [T][B][256] f16 pairs
    uint32_t* __restrict__ hx,           // [2][B_SZ*K2] fragment-major
    uint32_t* __restrict__ flags,        // [NBLK][16]
    float* __restrict__ last_state)      // [B][HID]
{
  __shared__ uint32_t w_lds[JSL * WPAD];   // 66 KB

  const int bk   = blockIdx.x;
  const int tid  = threadIdx.x;
  const int wv   = tid >> 6;
  const int lane = tid & 63;
  const int qr   = wv >> 1;
  const int qc   = wv & 1;
  const int row16 = lane & 15;
  const int kg    = lane >> 4;

  const int j_loc  = qc * 16 + row16;
  const int j_glob = bk * JSL + j_loc;
  const int b0     = qr * 16 + kg * 4;

  {
    const uint32_t* src = Wp16 + (size_t)bk * JSL * K2;
    for (int i = tid; i < JSL * K2; i += 256)
      w_lds[(i >> 9) * WPAD + (i & (K2 - 1))] = src[i];
  }

  const float a_j  = Avec[j_glob];
  const float it_j = 1.f / tau[j_glob];
  float h_old[4];
  #pragma unroll
  for (int r = 0; r < 4; ++r) h_old[r] = init_h[(b0 + r) * HID + j_glob];

  float prevC[4], tsC[4];
  #pragma unroll
  for (int r = 0; r < 4; ++r) {
    prevC[r] = pre[(size_t)(b0 + r) * HID + j_glob];
    tsC[r]   = tsp[(b0 + r) * T_SZ + 0];
  }

  __syncthreads();

  const uint32_t* brow = &w_lds[j_loc * WPAD];
  const int ab2 = (qr * 16 + row16) * 2;            // u64 base within chunk
  const int pub_base = (j_glob >> 3) * 128 + ((j_glob >> 1) & 3);

  for (int t = 0; t < T_SZ; ++t) {
    if (t > 0) {
      if (tid < 64) {
        const uint32_t tgt = (uint32_t)t;
        while (__hip_atomic_load(&flags[(tid & 31) * 16],
                                 __ATOMIC_RELAXED, __HIP_MEMORY_SCOPE_AGENT) < tgt)
          __builtin_amdgcn_s_sleep(1);
      }
      __syncthreads();
    }

    // A fragments (coalesced coherent 8B loads)
    const unsigned long long* hxr =
        (const unsigned long long*)(hx + (t & 1) * (B_SZ * K2));
    unsigned long long a64[64];
    #pragma unroll
    for (int kk = 0; kk < 32; ++kk) {
      const size_t base = (size_t)(kk * 4 + kg) * 64 + ab2;
      a64[2 * kk]     = __hip_atomic_load(&hxr[base],
                          __ATOMIC_RELAXED, __HIP_MEMORY_SCOPE_AGENT);
      a64[2 * kk + 1] = __hip_atomic_load(&hxr[base + 1],
                          __ATOMIC_RELAXED, __HIP_MEMORY_SCOPE_AGENT);
    }

    f32x4 acc = {0.f, 0.f, 0.f, 0.f};
    #pragma unroll
    for (int kk = 0; kk < 32; ++kk) {
      const uint4 av = make_uint4((uint32_t)a64[2 * kk],
                                  (uint32_t)(a64[2 * kk] >> 32),
                                  (uint32_t)a64[2 * kk + 1],
                                  (uint32_t)(a64[2 * kk + 1] >> 32));
      const uint4 bv = *(const uint4*)(brow + kk * 16 + kg * 4);
      acc = __builtin_amdgcn_mfma_f32_16x16x32_f16(
          __builtin_bit_cast(f16x8, av), __builtin_bit_cast(f16x8, bv),
          acc, 0, 0, 0);
    }

    float hn[4];
    #pragma unroll
    for (int r = 0; r < 4; ++r) {
      const float z = acc[r] + prevC[r];
      const float f = 1.f / (1.f + __expf(-z));
      hn[r] = (h_old[r] + tsC[r] * f * a_j) / (1.f + tsC[r] * (it_j + f));
      h_old[r] = hn[r];
    }

    uint32_t pkv[4];
    #pragma unroll
    for (int r = 0; r < 4; ++r) {
      const float partner = __shfl_xor(hn[r], 1);
      pkv[r] = pk16(hn[r], partner);
    }

    // critical path: ONLY the hx publishes before the drain + flag
    uint32_t* hxw = hx + ((t + 1) & 1) * (B_SZ * K2);
    if ((row16 & 1) == 0) {
      #pragma unroll
      for (int r = 0; r < 4; ++r)
        __hip_atomic_store(&hxw[pub_base + (b0 + r) * 4], pkv[r],
                           __ATOMIC_RELAXED, __HIP_MEMORY_SCOPE_AGENT);
    }

    __syncthreads();   // drains the hx publishes (all 4 waves)

    if (tid == 0)
      __hip_atomic_store(&flags[bk * 16], (uint32_t)(t + 1),
                         __ATOMIC_RELAXED, __HIP_MEMORY_SCOPE_AGENT);

    // off-critical-path: hseq16 + next-step prefetch (finish under next poll)
    if (bk < 16 && (row16 & 1) == 0) {
      #pragma unroll
      for (int r = 0; r < 4; ++r)
        hseq16[(size_t)t * (B_SZ * 256) + (b0 + r) * 256 + (j_glob >> 1)] = pkv[r];
    }
    const int tn = (t + 1 < T_SZ) ? t + 1 : t;
    #pragma unroll
    for (int r = 0; r < 4; ++r) {
      prevC[r] = pre[(size_t)tn * (B_SZ * HID) + (b0 + r) * HID + j_glob];
      tsC[r]   = tsp[(b0 + r) * T_SZ + tn];
    }
  }

  #pragma unroll
  for (int r = 0; r < 4; ++r)
    last_state[(b0 + r) * HID + j_glob] = h_old[r];
}

extern "C" void kernel_launch(void* const* d_in, const int* in_sizes, int n_in,
                              void* d_out, int out_size, void* d_ws, size_t ws_size,
                              hipStream_t stream)
{
  const float* inputs    = (const float*)d_in[0];
  const float* timespans = (const float*)d_in[1];
  const float* init_h    = (const float*)d_in[2];
  const float* W_in      = (const float*)d_in[3];
  const float* b_in      = (const float*)d_in[4];
  const float* W_x       = (const float*)d_in[5];
  const float* W_h       = (const float*)d_in[6];
  const float* b_cell    = (const float*)d_in[7];
  const float* tau       = (const float*)d_in[8];
  const float* A         = (const float*)d_in[9];
  const float* W_out     = (const float*)d_in[10];
  const float* b_out     = (const float*)d_in[11];
  float* out = (float*)d_out;

  float*    ws     = (float*)d_ws;
  float*    pre    = ws;
  uint32_t* hseq16 = (uint32_t*)(pre + (size_t)T_SZ * B_SZ * HID);
  uint32_t* in16   = hseq16 + (size_t)T_SZ * B_SZ * 256;
  float*    Wxi    = (float*)(in16 + (size_t)B_SZ * T_SZ * 256);
  uint32_t* wxi16  = (uint32_t*)(Wxi + (size_t)HID * IN_SZ);
  uint32_t* wh16   = wxi16 + (size_t)HID * (IN_SZ / 2);
  uint32_t* wout16 = wh16 + (size_t)HID * K2;
  float*    beff   = (float*)(wout16 + (size_t)OUT_SZ * (MOT / 2));
  uint32_t* hx     = (uint32_t*)(beff + HID);
  uint32_t* flags  = hx + 2 * B_SZ * K2;                 // NBLK*16 u32

  // K0: Wxi = W_x @ W_in (f32)
  gemm_tiled<false><<<dim3(IN_SZ / 64, HID / 64), 256, 0, stream>>>(
      W_x, W_in, nullptr, Wxi, HID, IN_SZ, SEN, SEN,
      1 << 30, (long long)IN_SZ, 0LL);

  bias_eff_kernel<<<HID / 256, 256, 0, stream>>>(W_x, b_in, b_cell, beff);

  // packs
  pack16_kernel<<<(B_SZ * T_SZ * IN_SZ / 2) / 256, 256, 0, stream>>>(inputs, in16);
  pack16_kernel<<<(HID * IN_SZ / 2) / 256, 256, 0, stream>>>(Wxi, wxi16);
  pack16_kernel<<<(HID * HID / 2) / 256, 256, 0, stream>>>(W_h, wh16);
  pack16_kernel<<<(OUT_SZ * MOT / 2) / 256, 256, 0, stream>>>(W_out, wout16);

  // K1 (MFMA): pre = in16 @ wxi16^T + beff, scattered to [t][b][h]
  gemm_mfma<<<dim3(HID / 128, (B_SZ * T_SZ) / 128), 256, 0, stream>>>(
      in16, wxi16, beff, pre, IN_SZ / 2,
      T_SZ, (long long)B_SZ * HID, (long long)HID);

  // init exchange parity-0; zero flags
  init_hx_kernel<<<(B_SZ * K2) / 256, 256, 0, stream>>>(init_h, hx);
  (void)hipMemsetAsync(flags, 0, NBLK * 16 * sizeof(uint32_t), stream);

  // scan — 32 co-resident blocks (R13 protocol, slim drain path)
  {
    const uint32_t* wh16c = (const uint32_t*)wh16;
    float* last_state = out + (size_t)B_SZ * T_SZ * OUT_SZ;
    void* args[] = {
      (void*)&init_h, (void*)&wh16c, (void*)&pre, (void*)&timespans,
      (void*)&A, (void*)&tau, (void*)&hseq16, (void*)&hx, (void*)&flags,
      (void*)&last_state
    };
    (void)hipLaunchCooperativeKernel((void*)scan_x_kernel, dim3(NBLK), dim3(256),
                                     args, 0, stream);
  }

  // K3 (MFMA): out = hseq16 @ wout16^T + b_out, scattered to [b][t][o]
  gemm_mfma<<<dim3(OUT_SZ / 128, (B_SZ * T_SZ) / 128), 256, 0, stream>>>(
      hseq16, wout16, b_out, out, MOT / 2,
      B_SZ, (long long)T_SZ * OUT_SZ, (long long)OUT_SZ);
}